// Round 7
// baseline (705.986 us; speedup 1.0000x reference)
//
#include <hip/hip_runtime.h>
#include <hip/hip_bf16.h>
#include <math.h>

// NOVAE forward. Round 16: encoder grid-occupancy fix (64x128 tiles).
//  - R15 post-mortem: sinkhorn at blended-cache ceiling (52 TB/s measured for
//    64MB/iter); VALU cut gave only -6.5%. Sinkhorn parked at 246 us.
//  - R16: non-sinkhorn region (413 us) attack. Encoder L0/L2 ran 128 blocks
//    (half GPU idle), L1 256. New gemm64_split (gemm_l3_fused tile structure,
//    runtime N/K, split-bf16x2 + ReLU + hi/lo epilogue) -> grids 256/512/256.
//    Per-output K-accumulation order unchanged (hh->lh->hl, same k0 order)
//    -> bitwise-identical output (absmax canary 1.192093e-07).
//  - everything else byte-identical to R15 (659.0 us measured).

namespace {

constexpr float REG = 0.05f;
constexpr int SINK_ITERS = 200;
constexpr int NBLK = 256;
constexpr int NTHR = 512;                        // 8 waves/block
constexpr int ROWS_PER_WAVE = 4096 / NBLK / 8;   // = 2
constexpr float STOP_EPS = 3e-6f;

typedef __attribute__((ext_vector_type(8))) short bf16x8;
typedef __attribute__((ext_vector_type(4))) float f32x4;
typedef __attribute__((ext_vector_type(2))) float f32x2;
typedef __attribute__((ext_vector_type(4))) int i32x4;

__device__ __forceinline__ unsigned short f2bf(float f)
{
    return __hip_bfloat16_raw(__float2bfloat16(f)).x;
}
__device__ __forceinline__ float bf2f(unsigned short u)
{
    return __uint_as_float(((unsigned int)u) << 16);
}

enum { EPI_SPLIT_RELU = 0, EPI_COST = 1 };

// ---------- 128x128 split-bf16x2 MFMA GEMM (R7 verbatim; cost GEMM) ----------
template<int EPI>
__global__ __launch_bounds__(256)
void gemm128_split(const unsigned short* __restrict__ Ah,
                   const unsigned short* __restrict__ Al,
                   const unsigned short* __restrict__ Bh,
                   const unsigned short* __restrict__ Bl,
                   const float* __restrict__ rb,
                   const float* __restrict__ aux,
                   void* __restrict__ C0,
                   unsigned short* __restrict__ C1,
                   float* __restrict__ maxOut,
                   int M, int N, int K)
{
    constexpr int LDK = 40;
    __shared__ unsigned short sAh[128 * LDK], sAl[128 * LDK];
    __shared__ unsigned short sBh[128 * LDK], sBl[128 * LDK];
    __shared__ float red[256];

    const int t = threadIdx.x;
    const int w = t >> 6, lane = t & 63;
    const int wr = (w >> 1) * 64, wc = (w & 1) * 64;
    const int am = lane & 15, aq = lane >> 4;
    const int row0 = blockIdx.y * 128, col0 = blockIdx.x * 128;
    const int sr0 = t >> 2, sc = (t & 3) << 3;

    f32x4 acc[4][4] = {};

    for (int k0 = 0; k0 < K; k0 += 32) {
        #pragma unroll
        for (int p = 0; p < 2; ++p) {
            const int r = sr0 + p * 64;
            const size_t ga = (size_t)(row0 + r) * K + k0 + sc;
            const size_t gb = (size_t)(col0 + r) * K + k0 + sc;
            *(uint4*)&sAh[r * LDK + sc] = *(const uint4*)&Ah[ga];
            *(uint4*)&sAl[r * LDK + sc] = *(const uint4*)&Al[ga];
            *(uint4*)&sBh[r * LDK + sc] = *(const uint4*)&Bh[gb];
            *(uint4*)&sBl[r * LDK + sc] = *(const uint4*)&Bl[gb];
        }
        __syncthreads();
        bf16x8 ah[4], al[4], bh[4], bl[4];
        #pragma unroll
        for (int i = 0; i < 4; ++i) {
            const int ra = (wr + i * 16 + am) * LDK + aq * 8;
            const int rbx = (wc + i * 16 + am) * LDK + aq * 8;
            ah[i] = *(const bf16x8*)&sAh[ra];
            al[i] = *(const bf16x8*)&sAl[ra];
            bh[i] = *(const bf16x8*)&sBh[rbx];
            bl[i] = *(const bf16x8*)&sBl[rbx];
        }
        #pragma unroll
        for (int i = 0; i < 4; ++i)
            #pragma unroll
            for (int j = 0; j < 4; ++j) {
                acc[i][j] = __builtin_amdgcn_mfma_f32_16x16x32_bf16(ah[i], bh[j], acc[i][j], 0, 0, 0);
                acc[i][j] = __builtin_amdgcn_mfma_f32_16x16x32_bf16(al[i], bh[j], acc[i][j], 0, 0, 0);
                acc[i][j] = __builtin_amdgcn_mfma_f32_16x16x32_bf16(ah[i], bl[j], acc[i][j], 0, 0, 0);
            }
        __syncthreads();
    }

    if constexpr (EPI == EPI_COST) {
        float lmax = 0.0f;
        #pragma unroll
        for (int i = 0; i < 4; ++i) {
            #pragma unroll
            for (int r = 0; r < 4; ++r) {
                const int row = row0 + wr + i * 16 + aq * 4 + r;
                const float znr = rb[row];
                #pragma unroll
                for (int j = 0; j < 4; ++j) {
                    const int col = col0 + wc + j * 16 + am;
                    const float v = fmaxf(znr + aux[col] - 2.0f * acc[i][j][r], 0.0f);
                    ((float*)C0)[(size_t)row * N + col] = v;
                    lmax = fmaxf(lmax, v);
                }
            }
        }
        red[t] = lmax;
        __syncthreads();
        for (int s = 128; s > 0; s >>= 1) {
            if (t < s) red[t] = fmaxf(red[t], red[t + s]);
            __syncthreads();
        }
        if (t == 0) atomicMax((int*)maxOut, __float_as_int(red[0]));
    } else {
        #pragma unroll
        for (int j = 0; j < 4; ++j) {
            const int col = col0 + wc + j * 16 + am;
            const float b = rb[col];
            #pragma unroll
            for (int i = 0; i < 4; ++i)
                #pragma unroll
                for (int r = 0; r < 4; ++r) {
                    const int row = row0 + wr + i * 16 + aq * 4 + r;
                    const float v = fmaxf(acc[i][j][r] + b, 0.0f);
                    const unsigned short hi = f2bf(v);
                    ((unsigned short*)C0)[(size_t)row * N + col] = hi;
                    C1[(size_t)row * N + col] = f2bf(v - bf2f(hi));
                }
        }
    }
}

// ---------- encoder hidden layers: 64x128-tile split MFMA, ReLU+split epi ----
// Tile structure identical to gemm_l3_fused (proven); runtime N,K; per-output
// K-accumulation order (hh, lh, hl per k0) matches gemm128_split -> bitwise
// identical results to the 128x128 version it replaces.
__global__ __launch_bounds__(256)
void gemm64_split(const unsigned short* __restrict__ Ah,
                  const unsigned short* __restrict__ Al,
                  const unsigned short* __restrict__ Bth,
                  const unsigned short* __restrict__ Btl,
                  const float* __restrict__ bias,
                  unsigned short* __restrict__ Ch,
                  unsigned short* __restrict__ Cl,
                  int N, int K)
{
    constexpr int LDK = 40;
    __shared__ unsigned short sAh[64 * LDK], sAl[64 * LDK];
    __shared__ unsigned short sBh[128 * LDK], sBl[128 * LDK];
    const int t = threadIdx.x;
    const int w = t >> 6, l = t & 63;
    const int am = l & 15, aq = l >> 4;
    const int row0 = blockIdx.y * 64;
    const int col0 = blockIdx.x * 128;
    const int sr = t >> 2, sk = (t & 3) << 3;

    f32x4 acc[8] = {};
    for (int k0 = 0; k0 < K; k0 += 32) {
        {
            const size_t ga = (size_t)(row0 + sr) * K + k0 + sk;
            *(uint4*)&sAh[sr * LDK + sk] = *(const uint4*)&Ah[ga];
            *(uint4*)&sAl[sr * LDK + sk] = *(const uint4*)&Al[ga];
        }
        #pragma unroll
        for (int p = 0; p < 2; ++p) {
            const int s = t + p * 256;
            const int rb = s >> 2, kb = (s & 3) << 3;
            const size_t gb = (size_t)(col0 + rb) * K + k0 + kb;
            *(uint4*)&sBh[rb * LDK + kb] = *(const uint4*)&Bth[gb];
            *(uint4*)&sBl[rb * LDK + kb] = *(const uint4*)&Btl[gb];
        }
        __syncthreads();
        const bf16x8 ah = *(const bf16x8*)&sAh[(w * 16 + am) * LDK + aq * 8];
        const bf16x8 al = *(const bf16x8*)&sAl[(w * 16 + am) * LDK + aq * 8];
        #pragma unroll
        for (int j = 0; j < 8; ++j) {
            const bf16x8 bh = *(const bf16x8*)&sBh[(j * 16 + am) * LDK + aq * 8];
            const bf16x8 bl = *(const bf16x8*)&sBl[(j * 16 + am) * LDK + aq * 8];
            acc[j] = __builtin_amdgcn_mfma_f32_16x16x32_bf16(ah, bh, acc[j], 0, 0, 0);
            acc[j] = __builtin_amdgcn_mfma_f32_16x16x32_bf16(al, bh, acc[j], 0, 0, 0);
            acc[j] = __builtin_amdgcn_mfma_f32_16x16x32_bf16(ah, bl, acc[j], 0, 0, 0);
        }
        __syncthreads();
    }

    #pragma unroll
    for (int j = 0; j < 8; ++j) {
        const int col = col0 + j * 16 + am;
        const float b = bias[col];
        #pragma unroll
        for (int r = 0; r < 4; ++r) {
            const int row = row0 + w * 16 + aq * 4 + r;
            const float v = fmaxf(acc[j][r] + b, 0.0f);
            const unsigned short hi = f2bf(v);
            Ch[(size_t)row * N + col] = hi;
            Cl[(size_t)row * N + col] = f2bf(v - bf2f(hi));
        }
    }
}

// ---------- encoder L3: split MFMA, 64x128 tile, fused split+rownorm ----------
__global__ __launch_bounds__(256)
void gemm_l3_fused(const unsigned short* __restrict__ Ah,
                   const unsigned short* __restrict__ Al,
                   const unsigned short* __restrict__ Bth,
                   const unsigned short* __restrict__ Btl,
                   const float* __restrict__ bias,
                   unsigned short* __restrict__ zh,
                   unsigned short* __restrict__ zl,
                   float* __restrict__ zn)
{
    constexpr int K = 512, N = 128, LDK = 40;
    __shared__ unsigned short sAh[64 * LDK], sAl[64 * LDK];
    __shared__ unsigned short sBh[128 * LDK], sBl[128 * LDK];
    const int t = threadIdx.x;
    const int w = t >> 6, l = t & 63;
    const int am = l & 15, aq = l >> 4;
    const int row0 = blockIdx.x * 64;
    const int sr = t >> 2, sk = (t & 3) << 3;

    f32x4 acc[8] = {};
    for (int k0 = 0; k0 < K; k0 += 32) {
        {
            const size_t ga = (size_t)(row0 + sr) * K + k0 + sk;
            *(uint4*)&sAh[sr * LDK + sk] = *(const uint4*)&Ah[ga];
            *(uint4*)&sAl[sr * LDK + sk] = *(const uint4*)&Al[ga];
        }
        #pragma unroll
        for (int p = 0; p < 2; ++p) {
            const int s = t + p * 256;
            const int rb = s >> 2, kb = (s & 3) << 3;
            const size_t gb = (size_t)rb * K + k0 + kb;
            *(uint4*)&sBh[rb * LDK + kb] = *(const uint4*)&Bth[gb];
            *(uint4*)&sBl[rb * LDK + kb] = *(const uint4*)&Btl[gb];
        }
        __syncthreads();
        const bf16x8 ah = *(const bf16x8*)&sAh[(w * 16 + am) * LDK + aq * 8];
        const bf16x8 al = *(const bf16x8*)&sAl[(w * 16 + am) * LDK + aq * 8];
        #pragma unroll
        for (int j = 0; j < 8; ++j) {
            const bf16x8 bh = *(const bf16x8*)&sBh[(j * 16 + am) * LDK + aq * 8];
            const bf16x8 bl = *(const bf16x8*)&sBl[(j * 16 + am) * LDK + aq * 8];
            acc[j] = __builtin_amdgcn_mfma_f32_16x16x32_bf16(ah, bh, acc[j], 0, 0, 0);
            acc[j] = __builtin_amdgcn_mfma_f32_16x16x32_bf16(al, bh, acc[j], 0, 0, 0);
            acc[j] = __builtin_amdgcn_mfma_f32_16x16x32_bf16(ah, bl, acc[j], 0, 0, 0);
        }
        __syncthreads();
    }

    float pn4[4] = {0.0f, 0.0f, 0.0f, 0.0f};
    #pragma unroll
    for (int j = 0; j < 8; ++j) {
        const int col = j * 16 + am;
        const float b = bias[col];
        #pragma unroll
        for (int r = 0; r < 4; ++r) {
            const int row = row0 + w * 16 + aq * 4 + r;
            const float z = acc[j][r] + b;
            const unsigned short hi = f2bf(z);
            zh[(size_t)row * N + col] = hi;
            zl[(size_t)row * N + col] = f2bf(z - bf2f(hi));
            pn4[r] = fmaf(z, z, pn4[r]);
        }
    }
    #pragma unroll
    for (int r = 0; r < 4; ++r) {
        float s = pn4[r];
        #pragma unroll
        for (int o = 8; o > 0; o >>= 1) s += __shfl_down(s, o, 16);
        if (am == 0) zn[row0 + w * 16 + aq * 4 + r] = s;
    }
}

// ---------- plain bf16 MFMA GEMM (decoder + coupling), 64x64 tile ----------
template<bool RELU, bool OUT_BF16, bool ROWSCALE>
__global__ __launch_bounds__(256)
void gemm_bf16_bt(const unsigned short* __restrict__ A,
                  const unsigned short* __restrict__ Bt,
                  const float* __restrict__ bias,
                  const float* __restrict__ rs,
                  void* __restrict__ C, int M, int N, int K)
{
    constexpr int BK = 32, LDK = 40;
    __shared__ unsigned short sA[64 * LDK];
    __shared__ unsigned short sB[64 * LDK];
    const int t = threadIdx.x;
    const int w = t >> 6, l = t & 63;
    const int row0 = blockIdx.y * 64, col0 = blockIdx.x * 64;
    const int sr = t >> 2, sk = (t & 3) << 3;
    const int am = l & 15, aq = l >> 4;

    f32x4 acc[4] = {};
    for (int k0 = 0; k0 < K; k0 += BK) {
        *(uint4*)&sA[sr * LDK + sk] = *(const uint4*)&A [(size_t)(row0 + sr) * K + k0 + sk];
        *(uint4*)&sB[sr * LDK + sk] = *(const uint4*)&Bt[(size_t)(col0 + sr) * K + k0 + sk];
        __syncthreads();
        const bf16x8 af = *(const bf16x8*)&sA[(w * 16 + am) * LDK + aq * 8];
        #pragma unroll
        for (int c = 0; c < 4; ++c) {
            const bf16x8 bfr = *(const bf16x8*)&sB[(c * 16 + am) * LDK + aq * 8];
            acc[c] = __builtin_amdgcn_mfma_f32_16x16x32_bf16(af, bfr, acc[c], 0, 0, 0);
        }
        __syncthreads();
    }
    #pragma unroll
    for (int c = 0; c < 4; ++c) {
        const int col = col0 + c * 16 + am;
        const float b = bias ? bias[col] : 0.0f;
        #pragma unroll
        for (int r = 0; r < 4; ++r) {
            const int row = row0 + w * 16 + aq * 4 + r;
            float v = acc[c][r] + b;
            if constexpr (RELU) v = fmaxf(v, 0.0f);
            if constexpr (ROWSCALE) v *= rs[row];
            if constexpr (OUT_BF16)
                ((unsigned short*)C)[(size_t)row * N + col] = f2bf(v);
            else
                ((float*)C)[(size_t)row * N + col] = v;
        }
    }
}

// ---------- prep bodies ----------
__device__ __forceinline__
void split_body(const float* __restrict__ x, unsigned short* __restrict__ hi,
                unsigned short* __restrict__ lo, int blk)
{
    const int i4 = (blk * 256 + threadIdx.x) * 4;
    const float4 v = *(const float4*)&x[i4];
    const float vv[4] = {v.x, v.y, v.z, v.w};
    unsigned short h[4], l[4];
    #pragma unroll
    for (int k = 0; k < 4; ++k) {
        h[k] = f2bf(vv[k]);
        l[k] = f2bf(vv[k] - bf2f(h[k]));
    }
    *(uint2*)&hi[i4] = *(uint2*)h;
    *(uint2*)&lo[i4] = *(uint2*)l;
}

__device__ __forceinline__
void wtrans_split_body(const float* __restrict__ W, unsigned short* __restrict__ Wth,
                       unsigned short* __restrict__ Wtl, int K, int N, int bx, int by)
{
    __shared__ float tile[32][33];
    const int tx = threadIdx.x & 31, ty4 = threadIdx.x >> 5;
    const int k0 = by * 32, n0 = bx * 32;
    #pragma unroll
    for (int r = 0; r < 4; ++r)
        tile[ty4 * 4 + r][tx] = W[(size_t)(k0 + ty4 * 4 + r) * N + n0 + tx];
    __syncthreads();
    #pragma unroll
    for (int r = 0; r < 4; ++r) {
        const float v = tile[tx][ty4 * 4 + r];
        const unsigned short h = f2bf(v);
        const size_t idx = (size_t)(n0 + ty4 * 4 + r) * K + k0 + tx;
        Wth[idx] = h;
        if (Wtl) Wtl[idx] = f2bf(v - bf2f(h));
    }
}

__global__ __launch_bounds__(256)
void prep_k(const float* __restrict__ zp,
            unsigned short* __restrict__ zph, unsigned short* __restrict__ zpl,
            const float* __restrict__ ew0, unsigned short* w0th, unsigned short* w0tl,
            const float* __restrict__ ew1, unsigned short* w1th, unsigned short* w1tl,
            const float* __restrict__ ew2, unsigned short* w2th, unsigned short* w2tl,
            const float* __restrict__ ew3, unsigned short* w3th, unsigned short* w3tl,
            const float* __restrict__ dw0, unsigned short* dwt0,
            const float* __restrict__ dw1, unsigned short* dwt1,
            const float* __restrict__ dw2, unsigned short* dwt2,
            const float* __restrict__ dw3, unsigned short* dwt3,
            float* __restrict__ pn,
            float* __restrict__ u, float* __restrict__ v,
            float* __restrict__ mx, int* __restrict__ dmax, int* __restrict__ bar)
{
    const int b = blockIdx.x;
    if (b < 512) {
        split_body(zp, zph, zpl, b);
    } else if (b < 1024) {
        const int j = b - 512; wtrans_split_body(ew0, w0th, w0tl, 1024, 512, j % 16, j / 16);
    } else if (b < 1536) {
        const int j = b - 1024; wtrans_split_body(ew1, w1th, w1tl, 512, 1024, j % 32, j / 32);
    } else if (b < 2048) {
        const int j = b - 1536; wtrans_split_body(ew2, w2th, w2tl, 1024, 512, j % 16, j / 16);
    } else if (b < 2112) {
        const int j = b - 2048; wtrans_split_body(ew3, w3th, w3tl, 512, 128, j % 4, j / 4);
    } else if (b < 2176) {
        const int j = b - 2112; wtrans_split_body(dw0, dwt0, nullptr, 128, 512, j % 16, j / 16);
    } else if (b < 2688) {
        const int j = b - 2176; wtrans_split_body(dw1, dwt1, nullptr, 512, 1024, j % 32, j / 32);
    } else if (b < 3200) {
        const int j = b - 2688; wtrans_split_body(dw2, dwt2, nullptr, 1024, 512, j % 16, j / 16);
    } else if (b < 3712) {
        const int j = b - 3200; wtrans_split_body(dw3, dwt3, nullptr, 512, 1024, j % 32, j / 32);
    } else if (b < 4736) {
        const int blk = b - 3712;
        const int row = blk * 4 + (threadIdx.x >> 6);
        const int lane = threadIdx.x & 63;
        const float2 vv = ((const float2*)&zp[(size_t)row * 128])[lane];
        float s = fmaf(vv.x, vv.x, vv.y * vv.y);
        #pragma unroll
        for (int o = 32; o > 0; o >>= 1) s += __shfl_down(s, o);
        if (lane == 0) pn[row] = s;
    } else {
        const int i = (b - 4736) * 256 + threadIdx.x;
        if (i < 4096) { u[i] = 1.0f / 4096.0f; v[i] = 1.0f / 4096.0f; }
        if (i == 0) *mx = 0.0f;
        if (b == 4736) bar[threadIdx.x] = 0;                     // 256 barrier flags
        if (b == 4737 && threadIdx.x < 32) dmax[threadIdx.x] = 0;
    }
}

__global__ __launch_bounds__(256)
void split_k(const float* __restrict__ x, unsigned short* __restrict__ hi,
             unsigned short* __restrict__ lo)
{
    split_body(x, hi, lo, blockIdx.x);
}

__global__ __launch_bounds__(256)
void vscale_t_k(const float* __restrict__ zp, const float* __restrict__ v,
                unsigned short* __restrict__ W2t)
{
    __shared__ float tile[32][33];
    const int tx = threadIdx.x & 31, ty4 = threadIdx.x >> 5;
    const int j0 = blockIdx.y * 32, d0 = blockIdx.x * 32;
    #pragma unroll
    for (int r = 0; r < 4; ++r) {
        const int j = j0 + ty4 * 4 + r;
        tile[ty4 * 4 + r][tx] = v[j] * zp[(size_t)j * 128 + d0 + tx];
    }
    __syncthreads();
    #pragma unroll
    for (int r = 0; r < 4; ++r)
        W2t[(size_t)(d0 + ty4 * 4 + r) * 4096 + j0 + tx] = f2bf(tile[tx][ty4 * 4 + r]);
}

__global__ __launch_bounds__(256)
void exp_transpose_k(const float* __restrict__ M,
                     unsigned short* __restrict__ Kb,
                     unsigned short* __restrict__ KTb,
                     const float* __restrict__ mx)
{
    __shared__ float tile[32][33];
    const float s = -1.0f / (REG * (*mx + 1e-12f));
    const int tx = threadIdx.x & 31, ty4 = threadIdx.x >> 5;
    const int i0 = blockIdx.y * 32, j0 = blockIdx.x * 32;
    #pragma unroll
    for (int r = 0; r < 4; ++r) {
        const int i = i0 + ty4 * 4 + r;
        const size_t idx = (size_t)i * 4096 + j0 + tx;
        const float k = expf(M[idx] * s);
        Kb[idx] = f2bf(k);
        tile[ty4 * 4 + r][tx] = k;
    }
    __syncthreads();
    #pragma unroll
    for (int r = 0; r < 4; ++r)
        KTb[(size_t)(j0 + ty4 * 4 + r) * 4096 + i0 + tx] = f2bf(tile[tx][ty4 * 4 + r]);
}

// ---------- Sinkhorn (R15 config, byte-identical) ----------

__device__ __forceinline__
void flag_barrier(int* flags, int gen, int bid)
{
    __syncthreads();
    if (threadIdx.x < 64) {
        if (threadIdx.x == 0)
            __hip_atomic_store(&flags[bid], gen, __ATOMIC_RELEASE, __HIP_MEMORY_SCOPE_AGENT);
        const int* fp = flags + threadIdx.x * 4;
        for (;;) {
            i32x4 f;
            asm volatile("global_load_dwordx4 %0, %1, off sc0 sc1\n\t"
                         "s_waitcnt vmcnt(0)"
                         : "=v"(f) : "v"(fp) : "memory");
            if (__all(f.x >= gen && f.y >= gen && f.z >= gen && f.w >= gen)) break;
            __builtin_amdgcn_s_sleep(1);
        }
    }
    __syncthreads();
}

__device__ __forceinline__
void stage_vec(const float* __restrict__ g, f32x4* As, f32x4* Bs)
{
    const int t = threadIdx.x;                    // [0,512)
    const f32x4* g0 = (const f32x4*)g + 2 * t;    // x4[2t], x4[2t+1]
    f32x4 r0, r1;
    asm volatile(
        "global_load_dwordx4 %0, %2, off sc0 sc1\n\t"
        "global_load_dwordx4 %1, %2, off offset:16 sc0 sc1\n\t"
        "s_waitcnt vmcnt(0)"
        : "=&v"(r0), "=&v"(r1)
        : "v"(g0) : "memory");
    As[t] = r0;
    Bs[t] = r1;
    __syncthreads();
}

__device__ __forceinline__ f32x2 bfpair(unsigned int m)
{
    f32x2 r;
    r.x = __uint_as_float(m << 16);
    r.y = __uint_as_float(m & 0xffff0000u);
    return r;
}

__device__ __forceinline__ void pkfma(f32x2& acc, f32x2 a, f32x2 b)
{
    asm("v_pk_fma_f32 %0, %1, %2, %0" : "+v"(acc) : "v"(a), "v"(b));
}

__device__ __forceinline__
void row_dot2_lds(const unsigned short* Mat, const f32x4* As, const f32x4* Bs,
                  int row0, int lane, float out[2])
{
    const uint4* m4[2];
    #pragma unroll
    for (int r = 0; r < 2; ++r)
        m4[r] = (const uint4*)(Mat + (size_t)(row0 + r) * 4096);

    f32x2 sA[2] = {{0.0f, 0.0f}, {0.0f, 0.0f}};   // (s0, s1)
    f32x2 sB[2] = {{0.0f, 0.0f}, {0.0f, 0.0f}};   // (s2, s3)
    #pragma unroll
    for (int w = 0; w < 8; ++w) {
        const int q = (w << 6) + lane;
        const f32x4 xa = As[q];
        const f32x4 xb = Bs[q];
        f32x2 xa01; xa01.x = xa.x; xa01.y = xa.y;
        f32x2 xa23; xa23.x = xa.z; xa23.y = xa.w;
        f32x2 xb01; xb01.x = xb.x; xb01.y = xb.y;
        f32x2 xb23; xb23.x = xb.z; xb23.y = xb.w;
        #pragma unroll
        for (int r = 0; r < 2; ++r) {
            const uint4 m = m4[r][q];
            pkfma(sA[r], bfpair(m.x), xa01);
            pkfma(sB[r], bfpair(m.y), xa23);
            pkfma(sA[r], bfpair(m.z), xb01);
            pkfma(sB[r], bfpair(m.w), xb23);
        }
    }
    #pragma unroll
    for (int r = 0; r < 2; ++r) {
        float s = (sA[r].x + sA[r].y) + (sB[r].x + sB[r].y);
        #pragma unroll
        for (int o = 32; o > 0; o >>= 1) s += __shfl_down(s, o);
        out[r] = s;
    }
}

__global__ __launch_bounds__(512, 4)
void sinkhorn_k(const unsigned short* __restrict__ Kb,
                const unsigned short* __restrict__ KTb,
                float* __restrict__ u, float* __restrict__ v,
                int* __restrict__ dmax, int* __restrict__ flags)
{
    static_assert(ROWS_PER_WAVE == 2, "row_dot2 assumes 2 rows/wave");
    __shared__ f32x4 As[512], Bs[512];
    const int wv   = threadIdx.x >> 6;            // 0..7
    const int lane = threadIdx.x & 63;
    const int bid  = blockIdx.x;
    const int row0 = bid * 16 + wv * 2;

    for (int it = 0; it < SINK_ITERS; ++it) {
        stage_vec(u, As, Bs);
        {
            float s[2];
            row_dot2_lds(KTb, As, Bs, row0, lane, s);
            if (lane == 0) {
                #pragma unroll
                for (int rr = 0; rr < 2; ++rr)
                    __hip_atomic_store(&v[row0 + rr], (1.0f / 4096.0f) / s[rr],
                                       __ATOMIC_RELAXED, __HIP_MEMORY_SCOPE_AGENT);
            }
        }
        flag_barrier(flags, 2 * it + 1, bid);

        stage_vec(v, As, Bs);
        const bool chk = ((it & 7) == 7);
        {
            float s[2];
            row_dot2_lds(Kb, As, Bs, row0, lane, s);
            if (lane == 0) {
                #pragma unroll
                for (int rr = 0; rr < 2; ++rr) {
                    const float nu = (1.0f / 4096.0f) / s[rr];
                    if (chk) {
                        const float ou = __hip_atomic_load(&u[row0 + rr],
                                           __ATOMIC_RELAXED, __HIP_MEMORY_SCOPE_AGENT);
                        const float d = fabsf(nu - ou) / (fabsf(ou) + 1e-37f);
                        atomicMax(&dmax[it >> 3], __float_as_int(d));
                    }
                    __hip_atomic_store(&u[row0 + rr], nu,
                                       __ATOMIC_RELAXED, __HIP_MEMORY_SCOPE_AGENT);
                }
            }
        }
        flag_barrier(flags, 2 * it + 2, bid);

        if (chk) {
            int dmi;
            const int* dp = &dmax[it >> 3];
            asm volatile("global_load_dword %0, %1, off sc0 sc1\n\t"
                         "s_waitcnt vmcnt(0)"
                         : "=v"(dmi) : "v"(dp) : "memory");
            if (__int_as_float(dmi) < STOP_EPS) break;
        }
    }
}

} // namespace

extern "C" void kernel_launch(void* const* d_in, const int* in_sizes, int n_in,
                              void* d_out, int out_size, void* d_ws, size_t ws_size,
                              hipStream_t stream)
{
    const float* x  = (const float*)d_in[0];
    const float* zp = (const float*)d_in[1];
    const float* ew[4] = {(const float*)d_in[2],  (const float*)d_in[4],
                          (const float*)d_in[6],  (const float*)d_in[8]};
    const float* eb[4] = {(const float*)d_in[3],  (const float*)d_in[5],
                          (const float*)d_in[7],  (const float*)d_in[9]};
    const float* dw[4] = {(const float*)d_in[10], (const float*)d_in[12],
                          (const float*)d_in[14], (const float*)d_in[16]};
    const float* db[4] = {(const float*)d_in[11], (const float*)d_in[13],
                          (const float*)d_in[15], (const float*)d_in[17]};
    float* out = (float*)d_out;

    char* w = (char*)d_ws;
    size_t off = 0;
    auto alloc = [&](size_t bytes) {
        void* p = (void*)(w + off);
        off += (bytes + 255) & ~size_t(255);
        return p;
    };
    float* Mm = (float*)alloc((size_t)4096 * 4096 * 4);                 // 64 MiB
    unsigned short* Kb  = (unsigned short*)alloc((size_t)4096 * 4096 * 2);
    unsigned short* KTb = (unsigned short*)alloc((size_t)4096 * 4096 * 2);
    unsigned short* dwt0 = (unsigned short*)alloc((size_t)512  * 128 * 2);
    unsigned short* dwt1 = (unsigned short*)alloc((size_t)1024 * 512 * 2);
    unsigned short* dwt2 = (unsigned short*)alloc((size_t)512  * 1024 * 2);
    unsigned short* dwt3 = (unsigned short*)alloc((size_t)1024 * 512 * 2);
    unsigned short* W2t  = (unsigned short*)alloc((size_t)128 * 4096 * 2);
    unsigned short* zh  = (unsigned short*)alloc((size_t)4096 * 128 * 2);
    unsigned short* zl  = (unsigned short*)alloc((size_t)4096 * 128 * 2);
    unsigned short* zph = (unsigned short*)alloc((size_t)4096 * 128 * 2);
    unsigned short* zpl = (unsigned short*)alloc((size_t)4096 * 128 * 2);
    float* zn   = (float*)alloc(4096 * 4);
    float* pn   = (float*)alloc(4096 * 4);
    float* u    = (float*)alloc(4096 * 4);
    float* v    = (float*)alloc(4096 * 4);
    float* mx   = (float*)alloc(256);
    int*   dmax = (int*)alloc(32 * 4);
    int*   bar  = (int*)alloc(256 * 4);               // 256 barrier flags
    (void)ws_size; (void)in_sizes; (void)n_in; (void)out_size;

    char* m = (char*)Mm;
    unsigned short* w0th = (unsigned short*)(m + (size_t)0  * (1u << 20));
    unsigned short* w0tl = (unsigned short*)(m + (size_t)1  * (1u << 20));
    unsigned short* w1th = (unsigned short*)(m + (size_t)2  * (1u << 20));
    unsigned short* w1tl = (unsigned short*)(m + (size_t)3  * (1u << 20));
    unsigned short* w2th = (unsigned short*)(m + (size_t)4  * (1u << 20));
    unsigned short* w2tl = (unsigned short*)(m + (size_t)5  * (1u << 20));
    unsigned short* a0h  = (unsigned short*)(m + (size_t)6  * (1u << 20));
    unsigned short* a0l  = (unsigned short*)(m + (size_t)10 * (1u << 20));
    unsigned short* a1h  = (unsigned short*)(m + (size_t)14 * (1u << 20));
    unsigned short* a1l  = (unsigned short*)(m + (size_t)22 * (1u << 20));
    unsigned short* a2h  = (unsigned short*)(m + (size_t)30 * (1u << 20));
    unsigned short* a2l  = (unsigned short*)(m + (size_t)34 * (1u << 20));
    unsigned short* w3th = (unsigned short*)(m + (size_t)38 * (1u << 20));
    unsigned short* w3tl = (unsigned short*)(m + (size_t)39 * (1u << 20));
    unsigned short* xh = (unsigned short*)Kb;
    unsigned short* xl = (unsigned short*)((char*)Kb + ((size_t)8 << 20));
    unsigned short* zselb = (unsigned short*)(m);
    unsigned short* a0b   = (unsigned short*)(m + (1u << 20));
    unsigned short* a1b   = (unsigned short*)(m + (5u << 20));
    unsigned short* a2b   = (unsigned short*)(m + (13u << 20));

    const dim3 blk(256);

    split_k<<<4096, blk, 0, stream>>>(x, xh, xl);
    prep_k<<<4752, blk, 0, stream>>>(zp, zph, zpl,
                                     ew[0], w0th, w0tl, ew[1], w1th, w1tl,
                                     ew[2], w2th, w2tl, ew[3], w3th, w3tl,
                                     dw[0], dwt0, dw[1], dwt1,
                                     dw[2], dwt2, dw[3], dwt3,
                                     pn, u, v, mx, dmax, bar);

    // ---- encoder: 64x128-tile split GEMMs (grids 256/512/256) ----
    gemm64_split<<<dim3(512/128,  4096/64), blk, 0, stream>>>(xh,  xl,  w0th, w0tl, eb[0], a0h, a0l, 512, 1024);
    gemm64_split<<<dim3(1024/128, 4096/64), blk, 0, stream>>>(a0h, a0l, w1th, w1tl, eb[1], a1h, a1l, 1024, 512);
    gemm64_split<<<dim3(512/128,  4096/64), blk, 0, stream>>>(a1h, a1l, w2th, w2tl, eb[2], a2h, a2l, 512, 1024);
    gemm_l3_fused<<<64, blk, 0, stream>>>(a2h, a2l, w3th, w3tl, eb[3], zh, zl, zn);

    gemm128_split<EPI_COST><<<dim3(4096/128, 4096/128), blk, 0, stream>>>(zh, zl, zph, zpl, zn, pn, Mm, nullptr, mx, 4096, 4096, 128);
    exp_transpose_k<<<dim3(128, 128), blk, 0, stream>>>(Mm, Kb, KTb, mx);

    sinkhorn_k<<<NBLK, dim3(NTHR), 0, stream>>>(Kb, KTb, u, v, dmax, bar);

    vscale_t_k<<<dim3(128/32, 4096/32), blk, 0, stream>>>(zp, v, W2t);
    gemm_bf16_bt<false,true,true><<<dim3(128/64, 4096/64), blk, 0, stream>>>(Kb, W2t, nullptr, u, zselb, 4096, 128, 4096);

    gemm_bf16_bt<true, true, false><<<dim3(512/64,  4096/64), blk, 0, stream>>>(zselb, dwt0, db[0], nullptr, a0b, 4096, 512, 128);
    gemm_bf16_bt<true, true, false><<<dim3(1024/64, 4096/64), blk, 0, stream>>>(a0b,   dwt1, db[1], nullptr, a1b, 4096, 1024, 512);
    gemm_bf16_bt<true, true, false><<<dim3(512/64,  4096/64), blk, 0, stream>>>(a1b,   dwt2, db[2], nullptr, a2b, 4096, 512, 1024);
    gemm_bf16_bt<false,false,false><<<dim3(1024/64, 4096/64), blk, 0, stream>>>(a2b,   dwt3, db[3], nullptr, out, 4096, 1024, 512);
}

// Round 8
// 656.449 us; speedup vs baseline: 1.0755x; 1.0755x over previous
//
#include <hip/hip_runtime.h>
#include <hip/hip_bf16.h>
#include <math.h>

// NOVAE forward. Round 17: revert R16 encoder regression + dispatch-merge probe.
//  - R16 post-mortem: 64x128 encoder tiles doubled B traffic (-47 us). Encoder
//    reverted to gemm128_split (R15 = 659 us known-good).
//  - Non-sinkhorn residual is ~400 us across R9-R15 but component arithmetic
//    sums to ~150-250 -> suspect per-dispatch overhead. R17 merges split_k
//    into prep_k (14 -> 13 dispatches, x-split blocks first) as the cheapest
//    discriminator: >=10 us saved => fuse decoder chain next; ~0 => attack
//    GEMM-internal efficiency next.
//  - Bodies verbatim -> bitwise-identical output (canary 1.192093e-07).

namespace {

constexpr float REG = 0.05f;
constexpr int SINK_ITERS = 200;
constexpr int NBLK = 256;
constexpr int NTHR = 512;                        // 8 waves/block
constexpr int ROWS_PER_WAVE = 4096 / NBLK / 8;   // = 2
constexpr float STOP_EPS = 3e-6f;

typedef __attribute__((ext_vector_type(8))) short bf16x8;
typedef __attribute__((ext_vector_type(4))) float f32x4;
typedef __attribute__((ext_vector_type(2))) float f32x2;
typedef __attribute__((ext_vector_type(4))) int i32x4;

__device__ __forceinline__ unsigned short f2bf(float f)
{
    return __hip_bfloat16_raw(__float2bfloat16(f)).x;
}
__device__ __forceinline__ float bf2f(unsigned short u)
{
    return __uint_as_float(((unsigned int)u) << 16);
}

enum { EPI_SPLIT_RELU = 0, EPI_COST = 1 };

// ---------- 128x128 split-bf16x2 MFMA GEMM (R7 verbatim) ----------
template<int EPI>
__global__ __launch_bounds__(256)
void gemm128_split(const unsigned short* __restrict__ Ah,
                   const unsigned short* __restrict__ Al,
                   const unsigned short* __restrict__ Bh,
                   const unsigned short* __restrict__ Bl,
                   const float* __restrict__ rb,
                   const float* __restrict__ aux,
                   void* __restrict__ C0,
                   unsigned short* __restrict__ C1,
                   float* __restrict__ maxOut,
                   int M, int N, int K)
{
    constexpr int LDK = 40;
    __shared__ unsigned short sAh[128 * LDK], sAl[128 * LDK];
    __shared__ unsigned short sBh[128 * LDK], sBl[128 * LDK];
    __shared__ float red[256];

    const int t = threadIdx.x;
    const int w = t >> 6, lane = t & 63;
    const int wr = (w >> 1) * 64, wc = (w & 1) * 64;
    const int am = lane & 15, aq = lane >> 4;
    const int row0 = blockIdx.y * 128, col0 = blockIdx.x * 128;
    const int sr0 = t >> 2, sc = (t & 3) << 3;

    f32x4 acc[4][4] = {};

    for (int k0 = 0; k0 < K; k0 += 32) {
        #pragma unroll
        for (int p = 0; p < 2; ++p) {
            const int r = sr0 + p * 64;
            const size_t ga = (size_t)(row0 + r) * K + k0 + sc;
            const size_t gb = (size_t)(col0 + r) * K + k0 + sc;
            *(uint4*)&sAh[r * LDK + sc] = *(const uint4*)&Ah[ga];
            *(uint4*)&sAl[r * LDK + sc] = *(const uint4*)&Al[ga];
            *(uint4*)&sBh[r * LDK + sc] = *(const uint4*)&Bh[gb];
            *(uint4*)&sBl[r * LDK + sc] = *(const uint4*)&Bl[gb];
        }
        __syncthreads();
        bf16x8 ah[4], al[4], bh[4], bl[4];
        #pragma unroll
        for (int i = 0; i < 4; ++i) {
            const int ra = (wr + i * 16 + am) * LDK + aq * 8;
            const int rbx = (wc + i * 16 + am) * LDK + aq * 8;
            ah[i] = *(const bf16x8*)&sAh[ra];
            al[i] = *(const bf16x8*)&sAl[ra];
            bh[i] = *(const bf16x8*)&sBh[rbx];
            bl[i] = *(const bf16x8*)&sBl[rbx];
        }
        #pragma unroll
        for (int i = 0; i < 4; ++i)
            #pragma unroll
            for (int j = 0; j < 4; ++j) {
                acc[i][j] = __builtin_amdgcn_mfma_f32_16x16x32_bf16(ah[i], bh[j], acc[i][j], 0, 0, 0);
                acc[i][j] = __builtin_amdgcn_mfma_f32_16x16x32_bf16(al[i], bh[j], acc[i][j], 0, 0, 0);
                acc[i][j] = __builtin_amdgcn_mfma_f32_16x16x32_bf16(ah[i], bl[j], acc[i][j], 0, 0, 0);
            }
        __syncthreads();
    }

    if constexpr (EPI == EPI_COST) {
        float lmax = 0.0f;
        #pragma unroll
        for (int i = 0; i < 4; ++i) {
            #pragma unroll
            for (int r = 0; r < 4; ++r) {
                const int row = row0 + wr + i * 16 + aq * 4 + r;
                const float znr = rb[row];
                #pragma unroll
                for (int j = 0; j < 4; ++j) {
                    const int col = col0 + wc + j * 16 + am;
                    const float v = fmaxf(znr + aux[col] - 2.0f * acc[i][j][r], 0.0f);
                    ((float*)C0)[(size_t)row * N + col] = v;
                    lmax = fmaxf(lmax, v);
                }
            }
        }
        red[t] = lmax;
        __syncthreads();
        for (int s = 128; s > 0; s >>= 1) {
            if (t < s) red[t] = fmaxf(red[t], red[t + s]);
            __syncthreads();
        }
        if (t == 0) atomicMax((int*)maxOut, __float_as_int(red[0]));
    } else {
        #pragma unroll
        for (int j = 0; j < 4; ++j) {
            const int col = col0 + wc + j * 16 + am;
            const float b = rb[col];
            #pragma unroll
            for (int i = 0; i < 4; ++i)
                #pragma unroll
                for (int r = 0; r < 4; ++r) {
                    const int row = row0 + wr + i * 16 + aq * 4 + r;
                    const float v = fmaxf(acc[i][j][r] + b, 0.0f);
                    const unsigned short hi = f2bf(v);
                    ((unsigned short*)C0)[(size_t)row * N + col] = hi;
                    C1[(size_t)row * N + col] = f2bf(v - bf2f(hi));
                }
        }
    }
}

// ---------- encoder L3: split MFMA, 64x128 tile, fused split+rownorm ----------
__global__ __launch_bounds__(256)
void gemm_l3_fused(const unsigned short* __restrict__ Ah,
                   const unsigned short* __restrict__ Al,
                   const unsigned short* __restrict__ Bth,
                   const unsigned short* __restrict__ Btl,
                   const float* __restrict__ bias,
                   unsigned short* __restrict__ zh,
                   unsigned short* __restrict__ zl,
                   float* __restrict__ zn)
{
    constexpr int K = 512, N = 128, LDK = 40;
    __shared__ unsigned short sAh[64 * LDK], sAl[64 * LDK];
    __shared__ unsigned short sBh[128 * LDK], sBl[128 * LDK];
    const int t = threadIdx.x;
    const int w = t >> 6, l = t & 63;
    const int am = l & 15, aq = l >> 4;
    const int row0 = blockIdx.x * 64;
    const int sr = t >> 2, sk = (t & 3) << 3;

    f32x4 acc[8] = {};
    for (int k0 = 0; k0 < K; k0 += 32) {
        {
            const size_t ga = (size_t)(row0 + sr) * K + k0 + sk;
            *(uint4*)&sAh[sr * LDK + sk] = *(const uint4*)&Ah[ga];
            *(uint4*)&sAl[sr * LDK + sk] = *(const uint4*)&Al[ga];
        }
        #pragma unroll
        for (int p = 0; p < 2; ++p) {
            const int s = t + p * 256;
            const int rb = s >> 2, kb = (s & 3) << 3;
            const size_t gb = (size_t)rb * K + k0 + kb;
            *(uint4*)&sBh[rb * LDK + kb] = *(const uint4*)&Bth[gb];
            *(uint4*)&sBl[rb * LDK + kb] = *(const uint4*)&Btl[gb];
        }
        __syncthreads();
        const bf16x8 ah = *(const bf16x8*)&sAh[(w * 16 + am) * LDK + aq * 8];
        const bf16x8 al = *(const bf16x8*)&sAl[(w * 16 + am) * LDK + aq * 8];
        #pragma unroll
        for (int j = 0; j < 8; ++j) {
            const bf16x8 bh = *(const bf16x8*)&sBh[(j * 16 + am) * LDK + aq * 8];
            const bf16x8 bl = *(const bf16x8*)&sBl[(j * 16 + am) * LDK + aq * 8];
            acc[j] = __builtin_amdgcn_mfma_f32_16x16x32_bf16(ah, bh, acc[j], 0, 0, 0);
            acc[j] = __builtin_amdgcn_mfma_f32_16x16x32_bf16(al, bh, acc[j], 0, 0, 0);
            acc[j] = __builtin_amdgcn_mfma_f32_16x16x32_bf16(ah, bl, acc[j], 0, 0, 0);
        }
        __syncthreads();
    }

    float pn4[4] = {0.0f, 0.0f, 0.0f, 0.0f};
    #pragma unroll
    for (int j = 0; j < 8; ++j) {
        const int col = j * 16 + am;
        const float b = bias[col];
        #pragma unroll
        for (int r = 0; r < 4; ++r) {
            const int row = row0 + w * 16 + aq * 4 + r;
            const float z = acc[j][r] + b;
            const unsigned short hi = f2bf(z);
            zh[(size_t)row * N + col] = hi;
            zl[(size_t)row * N + col] = f2bf(z - bf2f(hi));
            pn4[r] = fmaf(z, z, pn4[r]);
        }
    }
    #pragma unroll
    for (int r = 0; r < 4; ++r) {
        float s = pn4[r];
        #pragma unroll
        for (int o = 8; o > 0; o >>= 1) s += __shfl_down(s, o, 16);
        if (am == 0) zn[row0 + w * 16 + aq * 4 + r] = s;
    }
}

// ---------- plain bf16 MFMA GEMM (decoder + coupling), 64x64 tile ----------
template<bool RELU, bool OUT_BF16, bool ROWSCALE>
__global__ __launch_bounds__(256)
void gemm_bf16_bt(const unsigned short* __restrict__ A,
                  const unsigned short* __restrict__ Bt,
                  const float* __restrict__ bias,
                  const float* __restrict__ rs,
                  void* __restrict__ C, int M, int N, int K)
{
    constexpr int BK = 32, LDK = 40;
    __shared__ unsigned short sA[64 * LDK];
    __shared__ unsigned short sB[64 * LDK];
    const int t = threadIdx.x;
    const int w = t >> 6, l = t & 63;
    const int row0 = blockIdx.y * 64, col0 = blockIdx.x * 64;
    const int sr = t >> 2, sk = (t & 3) << 3;
    const int am = l & 15, aq = l >> 4;

    f32x4 acc[4] = {};
    for (int k0 = 0; k0 < K; k0 += BK) {
        *(uint4*)&sA[sr * LDK + sk] = *(const uint4*)&A [(size_t)(row0 + sr) * K + k0 + sk];
        *(uint4*)&sB[sr * LDK + sk] = *(const uint4*)&Bt[(size_t)(col0 + sr) * K + k0 + sk];
        __syncthreads();
        const bf16x8 af = *(const bf16x8*)&sA[(w * 16 + am) * LDK + aq * 8];
        #pragma unroll
        for (int c = 0; c < 4; ++c) {
            const bf16x8 bfr = *(const bf16x8*)&sB[(c * 16 + am) * LDK + aq * 8];
            acc[c] = __builtin_amdgcn_mfma_f32_16x16x32_bf16(af, bfr, acc[c], 0, 0, 0);
        }
        __syncthreads();
    }
    #pragma unroll
    for (int c = 0; c < 4; ++c) {
        const int col = col0 + c * 16 + am;
        const float b = bias ? bias[col] : 0.0f;
        #pragma unroll
        for (int r = 0; r < 4; ++r) {
            const int row = row0 + w * 16 + aq * 4 + r;
            float v = acc[c][r] + b;
            if constexpr (RELU) v = fmaxf(v, 0.0f);
            if constexpr (ROWSCALE) v *= rs[row];
            if constexpr (OUT_BF16)
                ((unsigned short*)C)[(size_t)row * N + col] = f2bf(v);
            else
                ((float*)C)[(size_t)row * N + col] = v;
        }
    }
}

// ---------- prep bodies ----------
__device__ __forceinline__
void split_body(const float* __restrict__ x, unsigned short* __restrict__ hi,
                unsigned short* __restrict__ lo, int blk)
{
    const int i4 = (blk * 256 + threadIdx.x) * 4;
    const float4 v = *(const float4*)&x[i4];
    const float vv[4] = {v.x, v.y, v.z, v.w};
    unsigned short h[4], l[4];
    #pragma unroll
    for (int k = 0; k < 4; ++k) {
        h[k] = f2bf(vv[k]);
        l[k] = f2bf(vv[k] - bf2f(h[k]));
    }
    *(uint2*)&hi[i4] = *(uint2*)h;
    *(uint2*)&lo[i4] = *(uint2*)l;
}

__device__ __forceinline__
void wtrans_split_body(const float* __restrict__ W, unsigned short* __restrict__ Wth,
                       unsigned short* __restrict__ Wtl, int K, int N, int bx, int by)
{
    __shared__ float tile[32][33];
    const int tx = threadIdx.x & 31, ty4 = threadIdx.x >> 5;
    const int k0 = by * 32, n0 = bx * 32;
    #pragma unroll
    for (int r = 0; r < 4; ++r)
        tile[ty4 * 4 + r][tx] = W[(size_t)(k0 + ty4 * 4 + r) * N + n0 + tx];
    __syncthreads();
    #pragma unroll
    for (int r = 0; r < 4; ++r) {
        const float v = tile[tx][ty4 * 4 + r];
        const unsigned short h = f2bf(v);
        const size_t idx = (size_t)(n0 + ty4 * 4 + r) * K + k0 + tx;
        Wth[idx] = h;
        if (Wtl) Wtl[idx] = f2bf(v - bf2f(h));
    }
}

// one kernel for ALL prep: x split (first, critical path), zp split, 8 weight
// transposes, rownorm(zp), init. 8848 blocks.
__global__ __launch_bounds__(256)
void prep_k(const float* __restrict__ x,
            unsigned short* __restrict__ xh, unsigned short* __restrict__ xl,
            const float* __restrict__ zp,
            unsigned short* __restrict__ zph, unsigned short* __restrict__ zpl,
            const float* __restrict__ ew0, unsigned short* w0th, unsigned short* w0tl,
            const float* __restrict__ ew1, unsigned short* w1th, unsigned short* w1tl,
            const float* __restrict__ ew2, unsigned short* w2th, unsigned short* w2tl,
            const float* __restrict__ ew3, unsigned short* w3th, unsigned short* w3tl,
            const float* __restrict__ dw0, unsigned short* dwt0,
            const float* __restrict__ dw1, unsigned short* dwt1,
            const float* __restrict__ dw2, unsigned short* dwt2,
            const float* __restrict__ dw3, unsigned short* dwt3,
            float* __restrict__ pn,
            float* __restrict__ u, float* __restrict__ v,
            float* __restrict__ mx, int* __restrict__ dmax, int* __restrict__ bar)
{
    const int b0 = blockIdx.x;
    if (b0 < 4096) {                              // x split (4096x1024)
        split_body(x, xh, xl, b0);
        return;
    }
    const int b = b0 - 4096;
    if (b < 512) {
        split_body(zp, zph, zpl, b);
    } else if (b < 1024) {
        const int j = b - 512; wtrans_split_body(ew0, w0th, w0tl, 1024, 512, j % 16, j / 16);
    } else if (b < 1536) {
        const int j = b - 1024; wtrans_split_body(ew1, w1th, w1tl, 512, 1024, j % 32, j / 32);
    } else if (b < 2048) {
        const int j = b - 1536; wtrans_split_body(ew2, w2th, w2tl, 1024, 512, j % 16, j / 16);
    } else if (b < 2112) {
        const int j = b - 2048; wtrans_split_body(ew3, w3th, w3tl, 512, 128, j % 4, j / 4);
    } else if (b < 2176) {
        const int j = b - 2112; wtrans_split_body(dw0, dwt0, nullptr, 128, 512, j % 16, j / 16);
    } else if (b < 2688) {
        const int j = b - 2176; wtrans_split_body(dw1, dwt1, nullptr, 512, 1024, j % 32, j / 32);
    } else if (b < 3200) {
        const int j = b - 2688; wtrans_split_body(dw2, dwt2, nullptr, 1024, 512, j % 16, j / 16);
    } else if (b < 3712) {
        const int j = b - 3200; wtrans_split_body(dw3, dwt3, nullptr, 512, 1024, j % 32, j / 32);
    } else if (b < 4736) {
        const int blk = b - 3712;
        const int row = blk * 4 + (threadIdx.x >> 6);
        const int lane = threadIdx.x & 63;
        const float2 vv = ((const float2*)&zp[(size_t)row * 128])[lane];
        float s = fmaf(vv.x, vv.x, vv.y * vv.y);
        #pragma unroll
        for (int o = 32; o > 0; o >>= 1) s += __shfl_down(s, o);
        if (lane == 0) pn[row] = s;
    } else {
        const int i = (b - 4736) * 256 + threadIdx.x;
        if (i < 4096) { u[i] = 1.0f / 4096.0f; v[i] = 1.0f / 4096.0f; }
        if (i == 0) *mx = 0.0f;
        if (b == 4736) bar[threadIdx.x] = 0;                     // 256 barrier flags
        if (b == 4737 && threadIdx.x < 32) dmax[threadIdx.x] = 0;
    }
}

__global__ __launch_bounds__(256)
void vscale_t_k(const float* __restrict__ zp, const float* __restrict__ v,
                unsigned short* __restrict__ W2t)
{
    __shared__ float tile[32][33];
    const int tx = threadIdx.x & 31, ty4 = threadIdx.x >> 5;
    const int j0 = blockIdx.y * 32, d0 = blockIdx.x * 32;
    #pragma unroll
    for (int r = 0; r < 4; ++r) {
        const int j = j0 + ty4 * 4 + r;
        tile[ty4 * 4 + r][tx] = v[j] * zp[(size_t)j * 128 + d0 + tx];
    }
    __syncthreads();
    #pragma unroll
    for (int r = 0; r < 4; ++r)
        W2t[(size_t)(d0 + ty4 * 4 + r) * 4096 + j0 + tx] = f2bf(tile[tx][ty4 * 4 + r]);
}

__global__ __launch_bounds__(256)
void exp_transpose_k(const float* __restrict__ M,
                     unsigned short* __restrict__ Kb,
                     unsigned short* __restrict__ KTb,
                     const float* __restrict__ mx)
{
    __shared__ float tile[32][33];
    const float s = -1.0f / (REG * (*mx + 1e-12f));
    const int tx = threadIdx.x & 31, ty4 = threadIdx.x >> 5;
    const int i0 = blockIdx.y * 32, j0 = blockIdx.x * 32;
    #pragma unroll
    for (int r = 0; r < 4; ++r) {
        const int i = i0 + ty4 * 4 + r;
        const size_t idx = (size_t)i * 4096 + j0 + tx;
        const float k = expf(M[idx] * s);
        Kb[idx] = f2bf(k);
        tile[ty4 * 4 + r][tx] = k;
    }
    __syncthreads();
    #pragma unroll
    for (int r = 0; r < 4; ++r)
        KTb[(size_t)(j0 + ty4 * 4 + r) * 4096 + i0 + tx] = f2bf(tile[tx][ty4 * 4 + r]);
}

// ---------- Sinkhorn (R15 config, byte-identical) ----------

__device__ __forceinline__
void flag_barrier(int* flags, int gen, int bid)
{
    __syncthreads();
    if (threadIdx.x < 64) {
        if (threadIdx.x == 0)
            __hip_atomic_store(&flags[bid], gen, __ATOMIC_RELEASE, __HIP_MEMORY_SCOPE_AGENT);
        const int* fp = flags + threadIdx.x * 4;
        for (;;) {
            i32x4 f;
            asm volatile("global_load_dwordx4 %0, %1, off sc0 sc1\n\t"
                         "s_waitcnt vmcnt(0)"
                         : "=v"(f) : "v"(fp) : "memory");
            if (__all(f.x >= gen && f.y >= gen && f.z >= gen && f.w >= gen)) break;
            __builtin_amdgcn_s_sleep(1);
        }
    }
    __syncthreads();
}

__device__ __forceinline__
void stage_vec(const float* __restrict__ g, f32x4* As, f32x4* Bs)
{
    const int t = threadIdx.x;                    // [0,512)
    const f32x4* g0 = (const f32x4*)g + 2 * t;    // x4[2t], x4[2t+1]
    f32x4 r0, r1;
    asm volatile(
        "global_load_dwordx4 %0, %2, off sc0 sc1\n\t"
        "global_load_dwordx4 %1, %2, off offset:16 sc0 sc1\n\t"
        "s_waitcnt vmcnt(0)"
        : "=&v"(r0), "=&v"(r1)
        : "v"(g0) : "memory");
    As[t] = r0;
    Bs[t] = r1;
    __syncthreads();
}

__device__ __forceinline__ f32x2 bfpair(unsigned int m)
{
    f32x2 r;
    r.x = __uint_as_float(m << 16);
    r.y = __uint_as_float(m & 0xffff0000u);
    return r;
}

__device__ __forceinline__ void pkfma(f32x2& acc, f32x2 a, f32x2 b)
{
    asm("v_pk_fma_f32 %0, %1, %2, %0" : "+v"(acc) : "v"(a), "v"(b));
}

__device__ __forceinline__
void row_dot2_lds(const unsigned short* Mat, const f32x4* As, const f32x4* Bs,
                  int row0, int lane, float out[2])
{
    const uint4* m4[2];
    #pragma unroll
    for (int r = 0; r < 2; ++r)
        m4[r] = (const uint4*)(Mat + (size_t)(row0 + r) * 4096);

    f32x2 sA[2] = {{0.0f, 0.0f}, {0.0f, 0.0f}};   // (s0, s1)
    f32x2 sB[2] = {{0.0f, 0.0f}, {0.0f, 0.0f}};   // (s2, s3)
    #pragma unroll
    for (int w = 0; w < 8; ++w) {
        const int q = (w << 6) + lane;
        const f32x4 xa = As[q];
        const f32x4 xb = Bs[q];
        f32x2 xa01; xa01.x = xa.x; xa01.y = xa.y;
        f32x2 xa23; xa23.x = xa.z; xa23.y = xa.w;
        f32x2 xb01; xb01.x = xb.x; xb01.y = xb.y;
        f32x2 xb23; xb23.x = xb.z; xb23.y = xb.w;
        #pragma unroll
        for (int r = 0; r < 2; ++r) {
            const uint4 m = m4[r][q];
            pkfma(sA[r], bfpair(m.x), xa01);
            pkfma(sB[r], bfpair(m.y), xa23);
            pkfma(sA[r], bfpair(m.z), xb01);
            pkfma(sB[r], bfpair(m.w), xb23);
        }
    }
    #pragma unroll
    for (int r = 0; r < 2; ++r) {
        float s = (sA[r].x + sA[r].y) + (sB[r].x + sB[r].y);
        #pragma unroll
        for (int o = 32; o > 0; o >>= 1) s += __shfl_down(s, o);
        out[r] = s;
    }
}

__global__ __launch_bounds__(512, 4)
void sinkhorn_k(const unsigned short* __restrict__ Kb,
                const unsigned short* __restrict__ KTb,
                float* __restrict__ u, float* __restrict__ v,
                int* __restrict__ dmax, int* __restrict__ flags)
{
    static_assert(ROWS_PER_WAVE == 2, "row_dot2 assumes 2 rows/wave");
    __shared__ f32x4 As[512], Bs[512];
    const int wv   = threadIdx.x >> 6;            // 0..7
    const int lane = threadIdx.x & 63;
    const int bid  = blockIdx.x;
    const int row0 = bid * 16 + wv * 2;

    for (int it = 0; it < SINK_ITERS; ++it) {
        stage_vec(u, As, Bs);
        {
            float s[2];
            row_dot2_lds(KTb, As, Bs, row0, lane, s);
            if (lane == 0) {
                #pragma unroll
                for (int rr = 0; rr < 2; ++rr)
                    __hip_atomic_store(&v[row0 + rr], (1.0f / 4096.0f) / s[rr],
                                       __ATOMIC_RELAXED, __HIP_MEMORY_SCOPE_AGENT);
            }
        }
        flag_barrier(flags, 2 * it + 1, bid);

        stage_vec(v, As, Bs);
        const bool chk = ((it & 7) == 7);
        {
            float s[2];
            row_dot2_lds(Kb, As, Bs, row0, lane, s);
            if (lane == 0) {
                #pragma unroll
                for (int rr = 0; rr < 2; ++rr) {
                    const float nu = (1.0f / 4096.0f) / s[rr];
                    if (chk) {
                        const float ou = __hip_atomic_load(&u[row0 + rr],
                                           __ATOMIC_RELAXED, __HIP_MEMORY_SCOPE_AGENT);
                        const float d = fabsf(nu - ou) / (fabsf(ou) + 1e-37f);
                        atomicMax(&dmax[it >> 3], __float_as_int(d));
                    }
                    __hip_atomic_store(&u[row0 + rr], nu,
                                       __ATOMIC_RELAXED, __HIP_MEMORY_SCOPE_AGENT);
                }
            }
        }
        flag_barrier(flags, 2 * it + 2, bid);

        if (chk) {
            int dmi;
            const int* dp = &dmax[it >> 3];
            asm volatile("global_load_dword %0, %1, off sc0 sc1\n\t"
                         "s_waitcnt vmcnt(0)"
                         : "=v"(dmi) : "v"(dp) : "memory");
            if (__int_as_float(dmi) < STOP_EPS) break;
        }
    }
}

} // namespace

extern "C" void kernel_launch(void* const* d_in, const int* in_sizes, int n_in,
                              void* d_out, int out_size, void* d_ws, size_t ws_size,
                              hipStream_t stream)
{
    const float* x  = (const float*)d_in[0];
    const float* zp = (const float*)d_in[1];
    const float* ew[4] = {(const float*)d_in[2],  (const float*)d_in[4],
                          (const float*)d_in[6],  (const float*)d_in[8]};
    const float* eb[4] = {(const float*)d_in[3],  (const float*)d_in[5],
                          (const float*)d_in[7],  (const float*)d_in[9]};
    const float* dw[4] = {(const float*)d_in[10], (const float*)d_in[12],
                          (const float*)d_in[14], (const float*)d_in[16]};
    const float* db[4] = {(const float*)d_in[11], (const float*)d_in[13],
                          (const float*)d_in[15], (const float*)d_in[17]};
    float* out = (float*)d_out;

    char* w = (char*)d_ws;
    size_t off = 0;
    auto alloc = [&](size_t bytes) {
        void* p = (void*)(w + off);
        off += (bytes + 255) & ~size_t(255);
        return p;
    };
    float* Mm = (float*)alloc((size_t)4096 * 4096 * 4);                 // 64 MiB
    unsigned short* Kb  = (unsigned short*)alloc((size_t)4096 * 4096 * 2);
    unsigned short* KTb = (unsigned short*)alloc((size_t)4096 * 4096 * 2);
    unsigned short* dwt0 = (unsigned short*)alloc((size_t)512  * 128 * 2);
    unsigned short* dwt1 = (unsigned short*)alloc((size_t)1024 * 512 * 2);
    unsigned short* dwt2 = (unsigned short*)alloc((size_t)512  * 1024 * 2);
    unsigned short* dwt3 = (unsigned short*)alloc((size_t)1024 * 512 * 2);
    unsigned short* W2t  = (unsigned short*)alloc((size_t)128 * 4096 * 2);
    unsigned short* zh  = (unsigned short*)alloc((size_t)4096 * 128 * 2);
    unsigned short* zl  = (unsigned short*)alloc((size_t)4096 * 128 * 2);
    unsigned short* zph = (unsigned short*)alloc((size_t)4096 * 128 * 2);
    unsigned short* zpl = (unsigned short*)alloc((size_t)4096 * 128 * 2);
    float* zn   = (float*)alloc(4096 * 4);
    float* pn   = (float*)alloc(4096 * 4);
    float* u    = (float*)alloc(4096 * 4);
    float* v    = (float*)alloc(4096 * 4);
    float* mx   = (float*)alloc(256);
    int*   dmax = (int*)alloc(32 * 4);
    int*   bar  = (int*)alloc(256 * 4);               // 256 barrier flags
    (void)ws_size; (void)in_sizes; (void)n_in; (void)out_size;

    char* m = (char*)Mm;
    unsigned short* w0th = (unsigned short*)(m + (size_t)0  * (1u << 20));
    unsigned short* w0tl = (unsigned short*)(m + (size_t)1  * (1u << 20));
    unsigned short* w1th = (unsigned short*)(m + (size_t)2  * (1u << 20));
    unsigned short* w1tl = (unsigned short*)(m + (size_t)3  * (1u << 20));
    unsigned short* w2th = (unsigned short*)(m + (size_t)4  * (1u << 20));
    unsigned short* w2tl = (unsigned short*)(m + (size_t)5  * (1u << 20));
    unsigned short* a0h  = (unsigned short*)(m + (size_t)6  * (1u << 20));
    unsigned short* a0l  = (unsigned short*)(m + (size_t)10 * (1u << 20));
    unsigned short* a1h  = (unsigned short*)(m + (size_t)14 * (1u << 20));
    unsigned short* a1l  = (unsigned short*)(m + (size_t)22 * (1u << 20));
    unsigned short* a2h  = (unsigned short*)(m + (size_t)30 * (1u << 20));
    unsigned short* a2l  = (unsigned short*)(m + (size_t)34 * (1u << 20));
    unsigned short* w3th = (unsigned short*)(m + (size_t)38 * (1u << 20));
    unsigned short* w3tl = (unsigned short*)(m + (size_t)39 * (1u << 20));
    unsigned short* xh = (unsigned short*)Kb;
    unsigned short* xl = (unsigned short*)((char*)Kb + ((size_t)8 << 20));
    unsigned short* zselb = (unsigned short*)(m);
    unsigned short* a0b   = (unsigned short*)(m + (1u << 20));
    unsigned short* a1b   = (unsigned short*)(m + (5u << 20));
    unsigned short* a2b   = (unsigned short*)(m + (13u << 20));

    const dim3 blk(256);

    // ---- all prep in one dispatch (x split first: critical path) ----
    prep_k<<<8848, blk, 0, stream>>>(x, xh, xl, zp, zph, zpl,
                                     ew[0], w0th, w0tl, ew[1], w1th, w1tl,
                                     ew[2], w2th, w2tl, ew[3], w3th, w3tl,
                                     dw[0], dwt0, dw[1], dwt1,
                                     dw[2], dwt2, dw[3], dwt3,
                                     pn, u, v, mx, dmax, bar);

    // ---- encoder: 1024 -> 512 -> 1024 -> 512 -> 128 (split-bf16x2 MFMA) ----
    gemm128_split<EPI_SPLIT_RELU><<<dim3(512/128,  4096/128), blk, 0, stream>>>(xh,  xl,  w0th, w0tl, eb[0], nullptr, a0h, a0l, nullptr, 4096, 512, 1024);
    gemm128_split<EPI_SPLIT_RELU><<<dim3(1024/128, 4096/128), blk, 0, stream>>>(a0h, a0l, w1th, w1tl, eb[1], nullptr, a1h, a1l, nullptr, 4096, 1024, 512);
    gemm128_split<EPI_SPLIT_RELU><<<dim3(512/128,  4096/128), blk, 0, stream>>>(a1h, a1l, w2th, w2tl, eb[2], nullptr, a2h, a2l, nullptr, 4096, 512, 1024);
    gemm_l3_fused<<<64, blk, 0, stream>>>(a2h, a2l, w3th, w3tl, eb[3], zh, zl, zn);

    gemm128_split<EPI_COST><<<dim3(4096/128, 4096/128), blk, 0, stream>>>(zh, zl, zph, zpl, zn, pn, Mm, nullptr, mx, 4096, 4096, 128);
    exp_transpose_k<<<dim3(128, 128), blk, 0, stream>>>(Mm, Kb, KTb, mx);

    sinkhorn_k<<<NBLK, dim3(NTHR), 0, stream>>>(Kb, KTb, u, v, dmax, bar);

    vscale_t_k<<<dim3(128/32, 4096/32), blk, 0, stream>>>(zp, v, W2t);
    gemm_bf16_bt<false,true,true><<<dim3(128/64, 4096/64), blk, 0, stream>>>(Kb, W2t, nullptr, u, zselb, 4096, 128, 4096);

    gemm_bf16_bt<true, true, false><<<dim3(512/64,  4096/64), blk, 0, stream>>>(zselb, dwt0, db[0], nullptr, a0b, 4096, 512, 128);
    gemm_bf16_bt<true, true, false><<<dim3(1024/64, 4096/64), blk, 0, stream>>>(a0b,   dwt1, db[1], nullptr, a1b, 4096, 1024, 512);
    gemm_bf16_bt<true, true, false><<<dim3(512/64,  4096/64), blk, 0, stream>>>(a1b,   dwt2, db[2], nullptr, a2b, 4096, 512, 1024);
    gemm_bf16_bt<false,false,false><<<dim3(1024/64, 4096/64), blk, 0, stream>>>(a2b,   dwt3, db[3], nullptr, out, 4096, 1024, 512);
}